// Round 5
// baseline (241.935 us; speedup 1.0000x reference)
//
#include <hip/hip_runtime.h>

#define HW_N (512 * 512)          // pixels per image plane
#define BINS 64
#define BPI  64                   // sub-blocks per image; 16*64 = 1024 blocks = 4/CU (all resident)
#define TPB  256
#define QPB  ((HW_N / 4) / BPI)   // float4 groups per block per stream = 1024
#define ITERS (QPB / TPB)         // 4 -> 32 gray floats held in registers per thread
#define MAXB 16

// workspace layout (all zero-initialized by k_init; atomics-only cross-block access)
#define OFF_DONE   0              // u32[MAXB]        per-image phase-A done counters
#define OFF_DONE2  64             // u32              global done counter (last-block-done)
#define OFF_MM     128            // u32[MAXB][4]     {enc(-mnx), enc(mxx), enc(-mny), enc(mxy)} via atomicMax
#define OFF_SUMS   512            // double[MAXB][6]  channel sums via atomicAdd(double)
#define OFF_HIST   2048           // u32[MAXB][2][BINS]
#define WS_INIT_WORDS 2560        // 10240 B total

__device__ __forceinline__ unsigned int f2ord(float f) {
    unsigned int u = __float_as_uint(f);
    return (u & 0x80000000u) ? ~u : (u | 0x80000000u);
}
__device__ __forceinline__ float ord2f(unsigned int u) {
    u = (u & 0x80000000u) ? (u ^ 0x80000000u) : ~u;
    return __uint_as_float(u);
}

__device__ __forceinline__ float grayf(float r, float g, float b) {
    return 0.299f * r + 0.587f * g + 0.114f * b;
}

__device__ __forceinline__ double waveSumD(double v) {
#pragma unroll
    for (int o = 32; o > 0; o >>= 1) v += __shfl_down(v, o);
    return v;
}
__device__ __forceinline__ float waveMinAll(float v) {
#pragma unroll
    for (int o = 32; o > 0; o >>= 1) v = fminf(v, __shfl_xor(v, o));
    return v;
}
__device__ __forceinline__ float waveMaxAll(float v) {
#pragma unroll
    for (int o = 32; o > 0; o >>= 1) v = fmaxf(v, __shfl_xor(v, o));
    return v;
}

// tiny init: zero counters + minmax + sums + hist (plain stores; kernel boundary
// makes them visible to the fused kernel's atomics — baseline-proven pattern)
__global__ void k_init(unsigned int* ws) {
    for (int i = threadIdx.x; i < WS_INIT_WORDS; i += TPB) ws[i] = 0u;
}

__global__ __launch_bounds__(TPB, 4) void k_fused(const float* __restrict__ x,
                                                  const float* __restrict__ y,
                                                  char* __restrict__ ws,
                                                  float* __restrict__ out, int B) {
    unsigned int* done   = (unsigned int*)(ws + OFF_DONE);
    unsigned int* done2  = (unsigned int*)(ws + OFF_DONE2);
    unsigned int* mm     = (unsigned int*)(ws + OFF_MM);
    double*       sums   = (double*)      (ws + OFF_SUMS);
    unsigned int* hist   = (unsigned int*)(ws + OFF_HIST);

    const int tid = threadIdx.x;
    const int blk = blockIdx.x;
    const int b   = blk / BPI;
    const int sub = blk % BPI;
    const int wave = tid >> 6;
    const int lane = tid & 63;

    const int q0 = sub * QPB;
    const size_t base = (size_t)b * 3 * HW_N;
    const float4* xr = (const float4*)(x + base);
    const float4* xg = (const float4*)(x + base + HW_N);
    const float4* xb = (const float4*)(x + base + 2 * HW_N);
    const float4* yr = (const float4*)(y + base);
    const float4* yg = (const float4*)(y + base + HW_N);
    const float4* yb = (const float4*)(y + base + 2 * HW_N);

    // ---------------- phase A: stream RGB once; keep grays in registers ----------------
    float s0 = 0.f, s1 = 0.f, s2 = 0.f;
    float t0 = 0.f, t1 = 0.f, t2 = 0.f;
    float mnx = 3.4e38f, mxx = -3.4e38f;
    float mny = 3.4e38f, mxy = -3.4e38f;
    float4 gxv[ITERS], gyv[ITERS];           // static-indexed -> stays in VGPRs

#pragma unroll
    for (int i = 0; i < ITERS; i++) {
        const int q = q0 + tid + i * TPB;
        float4 r = xr[q], g = xg[q], bl = xb[q];
        s0 += (r.x + r.y) + (r.z + r.w);
        s1 += (g.x + g.y) + (g.z + g.w);
        s2 += (bl.x + bl.y) + (bl.z + bl.w);
        {
            float g0 = grayf(r.x, g.x, bl.x), g1 = grayf(r.y, g.y, bl.y);
            float g2 = grayf(r.z, g.z, bl.z), g3 = grayf(r.w, g.w, bl.w);
            mnx = fminf(mnx, fminf(fminf(g0, g1), fminf(g2, g3)));
            mxx = fmaxf(mxx, fmaxf(fmaxf(g0, g1), fmaxf(g2, g3)));
            gxv[i] = make_float4(g0, g1, g2, g3);
        }
        r = yr[q]; g = yg[q]; bl = yb[q];
        t0 += (r.x + r.y) + (r.z + r.w);
        t1 += (g.x + g.y) + (g.z + g.w);
        t2 += (bl.x + bl.y) + (bl.z + bl.w);
        {
            float g0 = grayf(r.x, g.x, bl.x), g1 = grayf(r.y, g.y, bl.y);
            float g2 = grayf(r.z, g.z, bl.z), g3 = grayf(r.w, g.w, bl.w);
            mny = fminf(mny, fminf(fminf(g0, g1), fminf(g2, g3)));
            mxy = fmaxf(mxy, fmaxf(fmaxf(g0, g1), fmaxf(g2, g3)));
            gyv[i] = make_float4(g0, g1, g2, g3);
        }
    }

    // zero LDS histograms while phase-A reduction proceeds
    __shared__ unsigned int lh[8][BINS];     // [2 srcs][4 waves][64 bins]
    for (int i = tid; i < 8 * BINS; i += TPB) ((unsigned int*)lh)[i] = 0u;

    __shared__ double shs[6][TPB / 64];
    __shared__ float  shmn[2][TPB / 64];
    __shared__ float  shmx[2][TPB / 64];
    __shared__ float  bc[4];
    __shared__ unsigned int s_last;

    double d;
    d = waveSumD((double)s0); if (!lane) shs[0][wave] = d;
    d = waveSumD((double)s1); if (!lane) shs[1][wave] = d;
    d = waveSumD((double)s2); if (!lane) shs[2][wave] = d;
    d = waveSumD((double)t0); if (!lane) shs[3][wave] = d;
    d = waveSumD((double)t1); if (!lane) shs[4][wave] = d;
    d = waveSumD((double)t2); if (!lane) shs[5][wave] = d;
    float f;
    f = waveMinAll(mnx); if (!lane) shmn[0][wave] = f;
    f = waveMinAll(mny); if (!lane) shmn[1][wave] = f;
    f = waveMaxAll(mxx); if (!lane) shmx[0][wave] = f;
    f = waveMaxAll(mxy); if (!lane) shmx[1][wave] = f;
    __syncthreads();

    // ---- cross-block publish (atomics only -> coherent; release-inc orders them) ----
    if (tid == 0) {
        atomicAdd(&sums[b * 6 + 0], shs[0][0] + shs[0][1] + shs[0][2] + shs[0][3]);
        atomicAdd(&sums[b * 6 + 1], shs[1][0] + shs[1][1] + shs[1][2] + shs[1][3]);
        atomicAdd(&sums[b * 6 + 2], shs[2][0] + shs[2][1] + shs[2][2] + shs[2][3]);
        atomicAdd(&sums[b * 6 + 3], shs[3][0] + shs[3][1] + shs[3][2] + shs[3][3]);
        atomicAdd(&sums[b * 6 + 4], shs[4][0] + shs[4][1] + shs[4][2] + shs[4][3]);
        atomicAdd(&sums[b * 6 + 5], shs[5][0] + shs[5][1] + shs[5][2] + shs[5][3]);
        float a;
        a = fminf(fminf(shmn[0][0], shmn[0][1]), fminf(shmn[0][2], shmn[0][3]));
        atomicMax(&mm[b * 4 + 0], f2ord(-a));          // min as max of enc(-v); 0-init safe
        a = fmaxf(fmaxf(shmx[0][0], shmx[0][1]), fmaxf(shmx[0][2], shmx[0][3]));
        atomicMax(&mm[b * 4 + 1], f2ord(a));
        a = fminf(fminf(shmn[1][0], shmn[1][1]), fminf(shmn[1][2], shmn[1][3]));
        atomicMax(&mm[b * 4 + 2], f2ord(-a));
        a = fmaxf(fmaxf(shmx[1][0], shmx[1][1]), fmaxf(shmx[1][2], shmx[1][3]));
        atomicMax(&mm[b * 4 + 3], f2ord(a));

        __hip_atomic_fetch_add(&done[b], 1u, __ATOMIC_RELEASE, __HIP_MEMORY_SCOPE_AGENT);
        // spin until all 64 sibling blocks of this image published (1 lane only)
        while (__hip_atomic_load(&done[b], __ATOMIC_ACQUIRE, __HIP_MEMORY_SCOPE_AGENT) < (unsigned)BPI)
            __builtin_amdgcn_s_sleep(16);
        bc[0] = -ord2f(__hip_atomic_load(&mm[b * 4 + 0], __ATOMIC_RELAXED, __HIP_MEMORY_SCOPE_AGENT));
        bc[1] =  ord2f(__hip_atomic_load(&mm[b * 4 + 1], __ATOMIC_RELAXED, __HIP_MEMORY_SCOPE_AGENT));
        bc[2] = -ord2f(__hip_atomic_load(&mm[b * 4 + 2], __ATOMIC_RELAXED, __HIP_MEMORY_SCOPE_AGENT));
        bc[3] =  ord2f(__hip_atomic_load(&mm[b * 4 + 3], __ATOMIC_RELAXED, __HIP_MEMORY_SCOPE_AGENT));
    }
    __syncthreads();

    const float imnx = bc[0], imxx = bc[1], imny = bc[2], imxy = bc[3];
    const float rgx = (imxx > imnx) ? (imxx - imnx) : 1.0f;
    const float rgy = (imxy > imny) ? (imxy - imny) : 1.0f;

    // ---------------- phase B: histogram from registers ----------------
    unsigned int* hx = lh[wave];
    unsigned int* hy = lh[4 + wave];

#pragma unroll
    for (int i = 0; i < ITERS; i++) {
        {
            const float g[4] = { gxv[i].x, gxv[i].y, gxv[i].z, gxv[i].w };
#pragma unroll
            for (int j = 0; j < 4; j++) {
                float t = ((g[j] - imnx) / rgx) * 63.0f;   // match ref: div, *63, trunc, clip
                int id = (int)t;
                id = id < 0 ? 0 : (id > 63 ? 63 : id);
                atomicAdd(&hx[id], 1u);
            }
        }
        {
            const float g[4] = { gyv[i].x, gyv[i].y, gyv[i].z, gyv[i].w };
#pragma unroll
            for (int j = 0; j < 4; j++) {
                float t = ((g[j] - imny) / rgy) * 63.0f;
                int id = (int)t;
                id = id < 0 ? 0 : (id > 63 ? 63 : id);
                atomicAdd(&hy[id], 1u);
            }
        }
    }
    __syncthreads();

    // merge wave-hists -> per-image global hist (device-scope atomics)
    for (int i = tid; i < 2 * BINS; i += TPB) {
        const int src = i >> 6, bin = i & 63;
        unsigned int v = lh[src * 4 + 0][bin] + lh[src * 4 + 1][bin] +
                         lh[src * 4 + 2][bin] + lh[src * 4 + 3][bin];
        if (v) atomicAdd(&hist[(b * 2 + src) * BINS + bin], v);
    }

    // ---- last-block-done: ACQ_REL pairing gives visibility of all hist/sums/mm ----
    if (tid == 0) {
        unsigned int old = __hip_atomic_fetch_add(done2, 1u, __ATOMIC_ACQ_REL,
                                                  __HIP_MEMORY_SCOPE_AGENT);
        s_last = (old == gridDim.x - 1) ? 1u : 0u;
    }
    __syncthreads();
    if (!s_last) return;

    // ---------------- phase C: final loss (one block; atomic loads only) ----------------
    __shared__ double ssum[MAXB][6];
    __shared__ float  smm[MAXB][4];
    __shared__ double skl[TPB / 64], scb[TPB / 64];

    for (int t = tid; t < B * 6; t += TPB)
        ssum[t / 6][t % 6] = __hip_atomic_load(&sums[t], __ATOMIC_RELAXED, __HIP_MEMORY_SCOPE_AGENT);
    for (int t = tid; t < B * 4; t += TPB) {
        unsigned int e = __hip_atomic_load(&mm[t], __ATOMIC_RELAXED, __HIP_MEMORY_SCOPE_AGENT);
        smm[t >> 2][t & 3] = ((t & 1) == 0) ? -ord2f(e) : ord2f(e);   // even slots hold enc(-min)
    }
    __syncthreads();

    const float invN = 1.0f / (float)HW_N;         // 2^-18, exact
    double klt = 0.0, cbt = 0.0;

    for (int t = tid; t < B * BINS; t += TPB) {
        const int bb = t >> 6, bin = t & 63;
        const bool vldx = smm[bb][1] > smm[bb][0];
        const bool vldy = smm[bb][3] > smm[bb][2];
        const unsigned int cx = __hip_atomic_load(&hist[(bb * 2 + 0) * BINS + bin],
                                                  __ATOMIC_RELAXED, __HIP_MEMORY_SCOPE_AGENT);
        const unsigned int cy = __hip_atomic_load(&hist[(bb * 2 + 1) * BINS + bin],
                                                  __ATOMIC_RELAXED, __HIP_MEMORY_SCOPE_AGENT);
        const float xh = vldx ? (float)cx * invN : (1.0f / BINS);
        const float yh = vldy ? (float)cy * invN : (1.0f / BINS);
        const float log_in = logf(xh + 1e-8f);
        const float ylogy = (yh > 0.0f) ? yh * logf(yh) : 0.0f;
        klt += (double)ylogy - (double)yh * (double)log_in;
    }

    for (int t = tid; t < B * 3; t += TPB) {
        const int bb = t / 3, c = t - bb * 3;
        const double N = (double)HW_N;
        const double xbal = (ssum[bb][c] / N) /
                            ((ssum[bb][0] + ssum[bb][1] + ssum[bb][2]) / N + 1e-8);
        const double ybal = (ssum[bb][3 + c] / N) /
                            ((ssum[bb][3] + ssum[bb][4] + ssum[bb][5]) / N + 1e-8);
        cbt += fabs(xbal - ybal);
    }

    const double kw = waveSumD(klt);
    const double cw = waveSumD(cbt);
    if (!lane) { skl[wave] = kw; scb[wave] = cw; }
    __syncthreads();
    if (tid == 0) {
        double K = 0.0, C = 0.0;
        for (int i = 0; i < TPB / 64; i++) { K += skl[i]; C += scb[i]; }
        const double kl = K / (double)B;
        const double cb = C / (double)(B * 3);
        out[0] = (float)(10.0 * (cb + kl));
    }
}

extern "C" void kernel_launch(void* const* d_in, const int* in_sizes, int n_in,
                              void* d_out, int out_size, void* d_ws, size_t ws_size,
                              hipStream_t stream) {
    const float* x = (const float*)d_in[0];
    const float* y = (const float*)d_in[1];
    float* out = (float*)d_out;
    const int B = in_sizes[0] / (3 * HW_N);   // 16

    k_init<<<1, TPB, 0, stream>>>((unsigned int*)d_ws);
    k_fused<<<B * BPI, TPB, 0, stream>>>(x, y, (char*)d_ws, out, B);
}

// Round 6
// 158.447 us; speedup vs baseline: 1.5269x; 1.5269x over previous
//
#include <hip/hip_runtime.h>

#define HW_N (512 * 512)          // pixels per image plane
#define BINS 64
#define BPI  64                   // sub-blocks per image; == wave size (min/max + cb merges rely on this)
#define TPB  256
#define QPB  ((HW_N / 4) / BPI)   // float4 groups per block per stream = 1024
#define MAXB 16

// Per-block partials from pass 1. 64 B, written with plain stores (no init, no atomics).
struct Part {
    double sum[6];                // x r,g,b ; y r,g,b
    float  mn[2];                 // gray min: [0]=x, [1]=y
    float  mx[2];                 // gray max
};

// control block (zeroed by pass-1 block 0 with plain stores; kernel-end flush publishes)
struct Ctrl {
    unsigned int done[MAXB];      // per-image completion counters (pass 2)
    unsigned int done2;           // global completion counter (pass 2)
    unsigned int pad[3];
    double klacc;                 // sum of per-image KL contributions
    double cbacc;                 // sum of per-image |xbal-ybal| contributions
};

__device__ __forceinline__ float grayf(float r, float g, float b) {
    return 0.299f * r + 0.587f * g + 0.114f * b;
}

__device__ __forceinline__ double waveSumD(double v) {
#pragma unroll
    for (int o = 32; o > 0; o >>= 1) v += __shfl_down(v, o);
    return v;
}
// xor-butterfly: every lane ends with the reduction result
__device__ __forceinline__ float waveMinAll(float v) {
#pragma unroll
    for (int o = 32; o > 0; o >>= 1) v = fminf(v, __shfl_xor(v, o));
    return v;
}
__device__ __forceinline__ float waveMaxAll(float v) {
#pragma unroll
    for (int o = 32; o > 0; o >>= 1) v = fmaxf(v, __shfl_xor(v, o));
    return v;
}

// ---- pass 1: channel sums + gray min/max; stores gray planes; zeroes hist + ctrl ----
__global__ __launch_bounds__(TPB) void k_pass1(const float* __restrict__ x,
                                               const float* __restrict__ y,
                                               Part* __restrict__ part,
                                               unsigned int* __restrict__ img_hist,
                                               unsigned int* __restrict__ ctrl_w,
                                               float* __restrict__ gx,
                                               float* __restrict__ gy) {
    const int tid = threadIdx.x;
    const int blk = blockIdx.x;
    const int b   = blk / BPI;
    const int sub = blk % BPI;

    // zero per-image global histograms + control block (plain stores; kernel-end flush)
    if (sub == 0)
        for (int i = tid; i < 2 * BINS; i += TPB) img_hist[b * 2 * BINS + i] = 0u;
    if (blk == 0 && tid < sizeof(Ctrl) / 4) ctrl_w[tid] = 0u;

    const int q0 = sub * QPB;
    const size_t base = (size_t)b * 3 * HW_N;

    const float4* xr = (const float4*)(x + base);
    const float4* xg = (const float4*)(x + base + HW_N);
    const float4* xb = (const float4*)(x + base + 2 * HW_N);
    const float4* yr = (const float4*)(y + base);
    const float4* yg = (const float4*)(y + base + HW_N);
    const float4* yb = (const float4*)(y + base + 2 * HW_N);
    float4* gxp = (float4*)(gx + (size_t)b * HW_N);
    float4* gyp = (float4*)(gy + (size_t)b * HW_N);

    float s0 = 0.f, s1 = 0.f, s2 = 0.f;
    float t0 = 0.f, t1 = 0.f, t2 = 0.f;
    float mnx = 3.4e38f, mxx = -3.4e38f;
    float mny = 3.4e38f, mxy = -3.4e38f;

    for (int i = tid; i < QPB; i += TPB) {
        const int q = q0 + i;
        float4 r = xr[q], g = xg[q], bl = xb[q];
        s0 += (r.x + r.y) + (r.z + r.w);
        s1 += (g.x + g.y) + (g.z + g.w);
        s2 += (bl.x + bl.y) + (bl.z + bl.w);
        {
            float g0 = grayf(r.x, g.x, bl.x), g1 = grayf(r.y, g.y, bl.y);
            float g2 = grayf(r.z, g.z, bl.z), g3 = grayf(r.w, g.w, bl.w);
            mnx = fminf(mnx, fminf(fminf(g0, g1), fminf(g2, g3)));
            mxx = fmaxf(mxx, fmaxf(fmaxf(g0, g1), fmaxf(g2, g3)));
            gxp[q] = make_float4(g0, g1, g2, g3);   // exact values pass 2 will bin
        }
        r = yr[q]; g = yg[q]; bl = yb[q];
        t0 += (r.x + r.y) + (r.z + r.w);
        t1 += (g.x + g.y) + (g.z + g.w);
        t2 += (bl.x + bl.y) + (bl.z + bl.w);
        {
            float g0 = grayf(r.x, g.x, bl.x), g1 = grayf(r.y, g.y, bl.y);
            float g2 = grayf(r.z, g.z, bl.z), g3 = grayf(r.w, g.w, bl.w);
            mny = fminf(mny, fminf(fminf(g0, g1), fminf(g2, g3)));
            mxy = fmaxf(mxy, fmaxf(fmaxf(g0, g1), fmaxf(g2, g3)));
            gyp[q] = make_float4(g0, g1, g2, g3);
        }
    }

    const int wave = tid >> 6;
    const int lane = tid & 63;
    __shared__ double shs[6][TPB / 64];
    __shared__ float  shmn[2][TPB / 64];
    __shared__ float  shmx[2][TPB / 64];

    double d;
    d = waveSumD((double)s0); if (!lane) shs[0][wave] = d;
    d = waveSumD((double)s1); if (!lane) shs[1][wave] = d;
    d = waveSumD((double)s2); if (!lane) shs[2][wave] = d;
    d = waveSumD((double)t0); if (!lane) shs[3][wave] = d;
    d = waveSumD((double)t1); if (!lane) shs[4][wave] = d;
    d = waveSumD((double)t2); if (!lane) shs[5][wave] = d;
    float f;
    f = waveMinAll(mnx); if (!lane) shmn[0][wave] = f;
    f = waveMinAll(mny); if (!lane) shmn[1][wave] = f;
    f = waveMaxAll(mxx); if (!lane) shmx[0][wave] = f;
    f = waveMaxAll(mxy); if (!lane) shmx[1][wave] = f;
    __syncthreads();

    if (tid == 0) {
        Part& p = part[blk];
        p.sum[0] = shs[0][0] + shs[0][1] + shs[0][2] + shs[0][3];
        p.sum[1] = shs[1][0] + shs[1][1] + shs[1][2] + shs[1][3];
        p.sum[2] = shs[2][0] + shs[2][1] + shs[2][2] + shs[2][3];
        p.sum[3] = shs[3][0] + shs[3][1] + shs[3][2] + shs[3][3];
        p.sum[4] = shs[4][0] + shs[4][1] + shs[4][2] + shs[4][3];
        p.sum[5] = shs[5][0] + shs[5][1] + shs[5][2] + shs[5][3];
        p.mn[0] = fminf(fminf(shmn[0][0], shmn[0][1]), fminf(shmn[0][2], shmn[0][3]));
        p.mn[1] = fminf(fminf(shmn[1][0], shmn[1][1]), fminf(shmn[1][2], shmn[1][3]));
        p.mx[0] = fmaxf(fmaxf(shmx[0][0], shmx[0][1]), fmaxf(shmx[0][2], shmx[0][3]));
        p.mx[1] = fmaxf(fmaxf(shmx[1][0], shmx[1][1]), fmaxf(shmx[1][2], shmx[1][3]));
    }
}

// ---- pass 2: histogram + per-image tail + global tail (last-block-done, NO spins/fences) ----
__global__ __launch_bounds__(TPB) void k_pass2f(const float* __restrict__ gx,
                                                const float* __restrict__ gy,
                                                const Part* __restrict__ part,
                                                unsigned int* __restrict__ img_hist,
                                                Ctrl* __restrict__ ctrl,
                                                float* __restrict__ out, int B) {
    const int tid = threadIdx.x;
    const int blk = blockIdx.x;
    const int b   = blk / BPI;
    const int sub = blk % BPI;
    const int wave = tid >> 6;
    const int lane = tid & 63;

    // image-wide min/max: one Part slot per lane (BPI == 64), xor-butterfly reduce.
    const float4 mm = *(const float4*)&part[b * BPI + lane].mn[0];
    const float imnx = waveMinAll(mm.x);
    const float imny = waveMinAll(mm.y);
    const float imxx = waveMaxAll(mm.z);
    const float imxy = waveMaxAll(mm.w);
    const float rgx = (imxx > imnx) ? (imxx - imnx) : 1.0f;
    const float rgy = (imxy > imny) ? (imxy - imny) : 1.0f;

    __shared__ unsigned int lh[8][BINS];          // [2 srcs][4 waves][64 bins]
    for (int i = tid; i < 8 * BINS; i += TPB) ((unsigned int*)lh)[i] = 0u;
    __syncthreads();

    const int q0 = sub * QPB;
    const float4* gxp = (const float4*)(gx + (size_t)b * HW_N);
    const float4* gyp = (const float4*)(gy + (size_t)b * HW_N);

    unsigned int* hx = lh[wave];
    unsigned int* hy = lh[4 + wave];

    for (int i = tid; i < QPB; i += TPB) {
        const int q = q0 + i;
        {
            const float4 gv = gxp[q];
            const float g[4] = { gv.x, gv.y, gv.z, gv.w };
#pragma unroll
            for (int j = 0; j < 4; j++) {
                float t = ((g[j] - imnx) / rgx) * 63.0f;   // match ref: div, *63, trunc, clip
                int id = (int)t;
                id = id < 0 ? 0 : (id > 63 ? 63 : id);
                atomicAdd(&hx[id], 1u);
            }
        }
        {
            const float4 gv = gyp[q];
            const float g[4] = { gv.x, gv.y, gv.z, gv.w };
#pragma unroll
            for (int j = 0; j < 4; j++) {
                float t = ((g[j] - imny) / rgy) * 63.0f;
                int id = (int)t;
                id = id < 0 ? 0 : (id > 63 ? 63 : id);
                atomicAdd(&hy[id], 1u);
            }
        }
    }
    __syncthreads();

    // merge 4 wave-hists -> per-image global hist (device-scope atomics)
    for (int i = tid; i < 2 * BINS; i += TPB) {
        const int src = i >> 6, bin = i & 63;
        unsigned int v = lh[src * 4 + 0][bin] + lh[src * 4 + 1][bin] +
                         lh[src * 4 + 2][bin] + lh[src * 4 + 3][bin];
        if (v) atomicAdd(&img_hist[(b * 2 + src) * BINS + bin], v);
    }
    __syncthreads();   // drains every wave's vmcnt -> all hist atomics completed at coherent point

    // one release-RMW per block; the block that sees BPI-1 is last for its image (no waiting)
    __shared__ unsigned int s_li;
    if (tid == 0) {
        unsigned int old = __hip_atomic_fetch_add(&ctrl->done[b], 1u,
                                                  __ATOMIC_RELEASE, __HIP_MEMORY_SCOPE_AGENT);
        s_li = (old == BPI - 1) ? 1u : 0u;
    }
    __syncthreads();
    if (!s_li) return;

    // ---- per-image tail (runs on exactly one block per image, overlapped with others) ----
    if (tid == 0)   // single acquire: sync-with all 64 release-RMWs of this image
        (void)__hip_atomic_load(&ctrl->done[b], __ATOMIC_ACQUIRE, __HIP_MEMORY_SCOPE_AGENT);
    __syncthreads();

    const float invN = 1.0f / (float)HW_N;        // 2^-18, exact
    const bool vldx = imxx > imnx;
    const bool vldy = imxy > imny;

    if (tid < 64) {
        // wave 0: KL over the 64 bins (atomic loads hit the coherent point; no staleness)
        const unsigned int cx = __hip_atomic_load(&img_hist[(b * 2 + 0) * BINS + tid],
                                                  __ATOMIC_RELAXED, __HIP_MEMORY_SCOPE_AGENT);
        const unsigned int cy = __hip_atomic_load(&img_hist[(b * 2 + 1) * BINS + tid],
                                                  __ATOMIC_RELAXED, __HIP_MEMORY_SCOPE_AGENT);
        const float xh = vldx ? (float)cx * invN : (1.0f / BINS);
        const float yh = vldy ? (float)cy * invN : (1.0f / BINS);
        const float log_in = logf(xh + 1e-8f);
        const float ylogy = (yh > 0.0f) ? yh * logf(yh) : 0.0f;
        double term = (double)ylogy - (double)yh * (double)log_in;
        term = waveSumD(term);
        if (tid == 0) atomicAdd(&ctrl->klacc, term);
    } else if (tid < 128) {
        // wave 1: merge this image's 6 channel sums (64 Part slots, one per lane) + cb
        const int l = tid - 64;
        const double* ps = &part[b * BPI + l].sum[0];
        double s0 = waveSumD(ps[0]);
        double s1 = waveSumD(ps[1]);
        double s2 = waveSumD(ps[2]);
        double s3 = waveSumD(ps[3]);
        double s4 = waveSumD(ps[4]);
        double s5 = waveSumD(ps[5]);
        if (l == 0) {
            const double N = (double)HW_N;
            const double dx = (s0 + s1 + s2) / N + 1e-8;
            const double dy = (s3 + s4 + s5) / N + 1e-8;
            double cbt = 0.0;
            cbt += fabs((s0 / N) / dx - (s3 / N) / dy);
            cbt += fabs((s1 / N) / dx - (s4 / N) / dy);
            cbt += fabs((s2 / N) / dx - (s5 / N) / dy);
            atomicAdd(&ctrl->cbacc, cbt);
        }
    }
    __syncthreads();   // drain the two accumulator atomics

    if (tid == 0) {
        unsigned int old2 = __hip_atomic_fetch_add(&ctrl->done2, 1u,
                                                   __ATOMIC_ACQ_REL, __HIP_MEMORY_SCOPE_AGENT);
        if (old2 == (unsigned)(B - 1)) {
            const double K = __hip_atomic_load(&ctrl->klacc, __ATOMIC_RELAXED,
                                               __HIP_MEMORY_SCOPE_AGENT);
            const double C = __hip_atomic_load(&ctrl->cbacc, __ATOMIC_RELAXED,
                                               __HIP_MEMORY_SCOPE_AGENT);
            out[0] = (float)(10.0 * (C / (double)(B * 3) + K / (double)B));
        }
    }
}

extern "C" void kernel_launch(void* const* d_in, const int* in_sizes, int n_in,
                              void* d_out, int out_size, void* d_ws, size_t ws_size,
                              hipStream_t stream) {
    const float* x = (const float*)d_in[0];
    const float* y = (const float*)d_in[1];
    float* out = (float*)d_out;
    const int B = in_sizes[0] / (3 * HW_N);   // 16

    char* ws = (char*)d_ws;
    Part* part = (Part*)ws;                                        // 64 KiB
    unsigned int* img_hist = (unsigned int*)(ws + 65536);          // 8 KiB
    Ctrl* ctrl = (Ctrl*)(ws + 65536 + 8192);                       // ~96 B
    float* gx = (float*)(ws + (1 << 20));                          // 16 MiB
    float* gy = gx + (size_t)B * HW_N;                             // 16 MiB

    k_pass1<<<B * BPI, TPB, 0, stream>>>(x, y, part, img_hist,
                                         (unsigned int*)ctrl, gx, gy);
    k_pass2f<<<B * BPI, TPB, 0, stream>>>(gx, gy, part, img_hist, ctrl, out, B);
}

// Round 7
// 144.358 us; speedup vs baseline: 1.6759x; 1.0976x over previous
//
#include <hip/hip_runtime.h>

#define HW_N (512 * 512)          // pixels per image plane
#define BINS 64
#define BPI  64                   // sub-blocks per image; == wave size (min/max + cb merges rely on this)
#define TPB  256
#define QPB  ((HW_N / 4) / BPI)   // float4 groups per block per stream = 1024
#define ITER (QPB / TPB)          // 4 compile-time iterations
#define MAXB 16

// Per-block partials from pass 1. 64 B, written with plain stores (no init, no atomics).
struct Part {
    double sum[6];                // x r,g,b ; y r,g,b
    float  mn[2];                 // gray min: [0]=x, [1]=y
    float  mx[2];                 // gray max
};

// control block (zeroed by pass-1 block 0 with plain stores; kernel-end flush publishes).
// ALL access in pass 2 is RELAXED device-scope atomics -> coherent point, no cache maintenance.
struct Ctrl {
    unsigned int done[MAXB];      // per-image completion counters (pass 2)
    unsigned int done2;           // global completion counter (pass 2)
    unsigned int pad[3];
    double klacc;                 // sum of per-image KL contributions
    double cbacc;                 // sum of per-image |xbal-ybal| contributions
};

__device__ __forceinline__ float grayf(float r, float g, float b) {
    return 0.299f * r + 0.587f * g + 0.114f * b;
}

__device__ __forceinline__ double waveSumD(double v) {
#pragma unroll
    for (int o = 32; o > 0; o >>= 1) v += __shfl_down(v, o);
    return v;
}
// xor-butterfly: every lane ends with the reduction result
__device__ __forceinline__ float waveMinAll(float v) {
#pragma unroll
    for (int o = 32; o > 0; o >>= 1) v = fminf(v, __shfl_xor(v, o));
    return v;
}
__device__ __forceinline__ float waveMaxAll(float v) {
#pragma unroll
    for (int o = 32; o > 0; o >>= 1) v = fmaxf(v, __shfl_xor(v, o));
    return v;
}

// ---- pass 1: channel sums + gray min/max; stores gray planes; zeroes hist + ctrl ----
__global__ __launch_bounds__(TPB) void k_pass1(const float* __restrict__ x,
                                               const float* __restrict__ y,
                                               Part* __restrict__ part,
                                               unsigned int* __restrict__ img_hist,
                                               unsigned int* __restrict__ ctrl_w,
                                               float* __restrict__ gx,
                                               float* __restrict__ gy) {
    const int tid = threadIdx.x;
    const int blk = blockIdx.x;
    const int b   = blk / BPI;
    const int sub = blk % BPI;

    // zero per-image global histograms + control block (plain stores; kernel-end flush)
    if (sub == 0)
        for (int i = tid; i < 2 * BINS; i += TPB) img_hist[b * 2 * BINS + i] = 0u;
    if (blk == 0 && tid < sizeof(Ctrl) / 4) ctrl_w[tid] = 0u;

    const int q0 = sub * QPB;
    const size_t base = (size_t)b * 3 * HW_N;

    const float4* xr = (const float4*)(x + base);
    const float4* xg = (const float4*)(x + base + HW_N);
    const float4* xb = (const float4*)(x + base + 2 * HW_N);
    const float4* yr = (const float4*)(y + base);
    const float4* yg = (const float4*)(y + base + HW_N);
    const float4* yb = (const float4*)(y + base + 2 * HW_N);
    float4* gxp = (float4*)(gx + (size_t)b * HW_N);
    float4* gyp = (float4*)(gy + (size_t)b * HW_N);

    float s0 = 0.f, s1 = 0.f, s2 = 0.f;
    float t0 = 0.f, t1 = 0.f, t2 = 0.f;
    float mnx = 3.4e38f, mxx = -3.4e38f;
    float mny = 3.4e38f, mxy = -3.4e38f;

#pragma unroll
    for (int ii = 0; ii < ITER; ii++) {
        const int q = q0 + tid + ii * TPB;
        float4 r = xr[q], g = xg[q], bl = xb[q];
        s0 += (r.x + r.y) + (r.z + r.w);
        s1 += (g.x + g.y) + (g.z + g.w);
        s2 += (bl.x + bl.y) + (bl.z + bl.w);
        {
            float g0 = grayf(r.x, g.x, bl.x), g1 = grayf(r.y, g.y, bl.y);
            float g2 = grayf(r.z, g.z, bl.z), g3 = grayf(r.w, g.w, bl.w);
            mnx = fminf(mnx, fminf(fminf(g0, g1), fminf(g2, g3)));
            mxx = fmaxf(mxx, fmaxf(fmaxf(g0, g1), fmaxf(g2, g3)));
            gxp[q] = make_float4(g0, g1, g2, g3);   // exact values pass 2 will bin
        }
        r = yr[q]; g = yg[q]; bl = yb[q];
        t0 += (r.x + r.y) + (r.z + r.w);
        t1 += (g.x + g.y) + (g.z + g.w);
        t2 += (bl.x + bl.y) + (bl.z + bl.w);
        {
            float g0 = grayf(r.x, g.x, bl.x), g1 = grayf(r.y, g.y, bl.y);
            float g2 = grayf(r.z, g.z, bl.z), g3 = grayf(r.w, g.w, bl.w);
            mny = fminf(mny, fminf(fminf(g0, g1), fminf(g2, g3)));
            mxy = fmaxf(mxy, fmaxf(fmaxf(g0, g1), fmaxf(g2, g3)));
            gyp[q] = make_float4(g0, g1, g2, g3);
        }
    }

    const int wave = tid >> 6;
    const int lane = tid & 63;
    __shared__ double shs[6][TPB / 64];
    __shared__ float  shmn[2][TPB / 64];
    __shared__ float  shmx[2][TPB / 64];

    double d;
    d = waveSumD((double)s0); if (!lane) shs[0][wave] = d;
    d = waveSumD((double)s1); if (!lane) shs[1][wave] = d;
    d = waveSumD((double)s2); if (!lane) shs[2][wave] = d;
    d = waveSumD((double)t0); if (!lane) shs[3][wave] = d;
    d = waveSumD((double)t1); if (!lane) shs[4][wave] = d;
    d = waveSumD((double)t2); if (!lane) shs[5][wave] = d;
    float f;
    f = waveMinAll(mnx); if (!lane) shmn[0][wave] = f;
    f = waveMinAll(mny); if (!lane) shmn[1][wave] = f;
    f = waveMaxAll(mxx); if (!lane) shmx[0][wave] = f;
    f = waveMaxAll(mxy); if (!lane) shmx[1][wave] = f;
    __syncthreads();

    if (tid == 0) {
        Part& p = part[blk];
        p.sum[0] = shs[0][0] + shs[0][1] + shs[0][2] + shs[0][3];
        p.sum[1] = shs[1][0] + shs[1][1] + shs[1][2] + shs[1][3];
        p.sum[2] = shs[2][0] + shs[2][1] + shs[2][2] + shs[2][3];
        p.sum[3] = shs[3][0] + shs[3][1] + shs[3][2] + shs[3][3];
        p.sum[4] = shs[4][0] + shs[4][1] + shs[4][2] + shs[4][3];
        p.sum[5] = shs[5][0] + shs[5][1] + shs[5][2] + shs[5][3];
        p.mn[0] = fminf(fminf(shmn[0][0], shmn[0][1]), fminf(shmn[0][2], shmn[0][3]));
        p.mn[1] = fminf(fminf(shmn[1][0], shmn[1][1]), fminf(shmn[1][2], shmn[1][3]));
        p.mx[0] = fmaxf(fmaxf(shmx[0][0], shmx[0][1]), fmaxf(shmx[0][2], shmx[0][3]));
        p.mx[1] = fmaxf(fmaxf(shmx[1][0], shmx[1][1]), fmaxf(shmx[1][2], shmx[1][3]));
    }
}

// ---- pass 2: histogram + per-image tail + global tail (RELAXED atomics only) ----
// Ordering argument: __syncthreads() drains vmcnt(0) for every wave (compiler emits the
// full s_waitcnt before s_barrier), so all of this block's hist atomicAdds are COMPLETE
// at the coherent point before tid0's relaxed done-counter add issues. The coherent
// point serializes; the block that observes count==BPI-1 therefore sees all 64 blocks'
// hist adds via relaxed atomic loads. No release/acquire -> no L2 writeback/invalidate.
__global__ __launch_bounds__(TPB) void k_pass2f(const float* __restrict__ gx,
                                                const float* __restrict__ gy,
                                                const Part* __restrict__ part,
                                                unsigned int* __restrict__ img_hist,
                                                Ctrl* __restrict__ ctrl,
                                                float* __restrict__ out, int B) {
    const int tid = threadIdx.x;
    const int blk = blockIdx.x;
    const int b   = blk / BPI;
    const int sub = blk % BPI;
    const int wave = tid >> 6;
    const int lane = tid & 63;

    // image-wide min/max: one Part slot per lane (BPI == 64), xor-butterfly reduce.
    const float4 mm = *(const float4*)&part[b * BPI + lane].mn[0];
    const float imnx = waveMinAll(mm.x);
    const float imny = waveMinAll(mm.y);
    const float imxx = waveMaxAll(mm.z);
    const float imxy = waveMaxAll(mm.w);
    const float rgx = (imxx > imnx) ? (imxx - imnx) : 1.0f;
    const float rgy = (imxy > imny) ? (imxy - imny) : 1.0f;

    __shared__ unsigned int lh[8][BINS];          // [2 srcs][4 waves][64 bins]
    for (int i = tid; i < 8 * BINS; i += TPB) ((unsigned int*)lh)[i] = 0u;
    __syncthreads();

    const int q0 = sub * QPB;
    const float4* gxp = (const float4*)(gx + (size_t)b * HW_N);
    const float4* gyp = (const float4*)(gy + (size_t)b * HW_N);

    unsigned int* hx = lh[wave];
    unsigned int* hy = lh[4 + wave];

#pragma unroll
    for (int ii = 0; ii < ITER; ii++) {
        const int q = q0 + tid + ii * TPB;
        {
            const float4 gv = gxp[q];
            const float g[4] = { gv.x, gv.y, gv.z, gv.w };
#pragma unroll
            for (int j = 0; j < 4; j++) {
                float t = ((g[j] - imnx) / rgx) * 63.0f;   // match ref: div, *63, trunc, clip
                int id = (int)t;
                id = id < 0 ? 0 : (id > 63 ? 63 : id);
                atomicAdd(&hx[id], 1u);
            }
        }
        {
            const float4 gv = gyp[q];
            const float g[4] = { gv.x, gv.y, gv.z, gv.w };
#pragma unroll
            for (int j = 0; j < 4; j++) {
                float t = ((g[j] - imny) / rgy) * 63.0f;
                int id = (int)t;
                id = id < 0 ? 0 : (id > 63 ? 63 : id);
                atomicAdd(&hy[id], 1u);
            }
        }
    }
    __syncthreads();

    // merge 4 wave-hists -> per-image global hist (relaxed device-scope atomics)
    for (int i = tid; i < 2 * BINS; i += TPB) {
        const int src = i >> 6, bin = i & 63;
        unsigned int v = lh[src * 4 + 0][bin] + lh[src * 4 + 1][bin] +
                         lh[src * 4 + 2][bin] + lh[src * 4 + 3][bin];
        if (v) atomicAdd(&img_hist[(b * 2 + src) * BINS + bin], v);
    }
    __syncthreads();   // drains vmcnt -> all hist atomics complete at the coherent point

    // one RELAXED RMW per block; the block that sees BPI-1 is last for its image
    __shared__ unsigned int s_li;
    if (tid == 0) {
        unsigned int old = __hip_atomic_fetch_add(&ctrl->done[b], 1u,
                                                  __ATOMIC_RELAXED, __HIP_MEMORY_SCOPE_AGENT);
        s_li = (old == BPI - 1) ? 1u : 0u;
    }
    __syncthreads();
    if (!s_li) return;

    // ---- per-image tail (exactly one block per image; overlaps other images' work) ----
    const float invN = 1.0f / (float)HW_N;        // 2^-18, exact
    const bool vldx = imxx > imnx;
    const bool vldy = imxy > imny;

    if (tid < 64) {
        // wave 0: KL over the 64 bins (relaxed atomic loads hit the coherent point)
        const unsigned int cx = __hip_atomic_load(&img_hist[(b * 2 + 0) * BINS + tid],
                                                  __ATOMIC_RELAXED, __HIP_MEMORY_SCOPE_AGENT);
        const unsigned int cy = __hip_atomic_load(&img_hist[(b * 2 + 1) * BINS + tid],
                                                  __ATOMIC_RELAXED, __HIP_MEMORY_SCOPE_AGENT);
        const float xh = vldx ? (float)cx * invN : (1.0f / BINS);
        const float yh = vldy ? (float)cy * invN : (1.0f / BINS);
        const float log_in = logf(xh + 1e-8f);
        const float ylogy = (yh > 0.0f) ? yh * logf(yh) : 0.0f;
        double term = (double)ylogy - (double)yh * (double)log_in;
        term = waveSumD(term);
        if (tid == 0) atomicAdd(&ctrl->klacc, term);
    } else if (tid < 128) {
        // wave 1: merge this image's 6 channel sums (64 Part slots, one per lane) + cb
        const int l = tid - 64;
        const double* ps = &part[b * BPI + l].sum[0];
        double s0 = waveSumD(ps[0]);
        double s1 = waveSumD(ps[1]);
        double s2 = waveSumD(ps[2]);
        double s3 = waveSumD(ps[3]);
        double s4 = waveSumD(ps[4]);
        double s5 = waveSumD(ps[5]);
        if (l == 0) {
            const double N = (double)HW_N;
            const double dx = (s0 + s1 + s2) / N + 1e-8;
            const double dy = (s3 + s4 + s5) / N + 1e-8;
            double cbt = 0.0;
            cbt += fabs((s0 / N) / dx - (s3 / N) / dy);
            cbt += fabs((s1 / N) / dx - (s4 / N) / dy);
            cbt += fabs((s2 / N) / dx - (s5 / N) / dy);
            atomicAdd(&ctrl->cbacc, cbt);
        }
    }
    __syncthreads();   // drain the two accumulator atomics before the done2 add

    if (tid == 0) {
        unsigned int old2 = __hip_atomic_fetch_add(&ctrl->done2, 1u,
                                                   __ATOMIC_RELAXED, __HIP_MEMORY_SCOPE_AGENT);
        if (old2 == (unsigned)(B - 1)) {
            const double K = __hip_atomic_load(&ctrl->klacc, __ATOMIC_RELAXED,
                                               __HIP_MEMORY_SCOPE_AGENT);
            const double C = __hip_atomic_load(&ctrl->cbacc, __ATOMIC_RELAXED,
                                               __HIP_MEMORY_SCOPE_AGENT);
            out[0] = (float)(10.0 * (C / (double)(B * 3) + K / (double)B));
        }
    }
}

extern "C" void kernel_launch(void* const* d_in, const int* in_sizes, int n_in,
                              void* d_out, int out_size, void* d_ws, size_t ws_size,
                              hipStream_t stream) {
    const float* x = (const float*)d_in[0];
    const float* y = (const float*)d_in[1];
    float* out = (float*)d_out;
    const int B = in_sizes[0] / (3 * HW_N);   // 16

    char* ws = (char*)d_ws;
    Part* part = (Part*)ws;                                        // 64 KiB
    unsigned int* img_hist = (unsigned int*)(ws + 65536);          // 8 KiB
    Ctrl* ctrl = (Ctrl*)(ws + 65536 + 8192);                       // 96 B
    float* gx = (float*)(ws + (1 << 20));                          // 16 MiB
    float* gy = gx + (size_t)B * HW_N;                             // 16 MiB

    k_pass1<<<B * BPI, TPB, 0, stream>>>(x, y, part, img_hist,
                                         (unsigned int*)ctrl, gx, gy);
    k_pass2f<<<B * BPI, TPB, 0, stream>>>(gx, gy, part, img_hist, ctrl, out, B);
}